// Round 15
// baseline (465.400 us; speedup 1.0000x reference)
//
#include <hip/hip_runtime.h>
#include <hip/hip_bf16.h>

// LocalizedFiltering: two shifted 2-tap causal convs + residual + RMSNorm.
// Fused-K form: A'[u] = U[u] ‖ U[u+1] (U = Xbf for GEMM1, A2 for GEMM2):
//   A2[u+1] = Xbf'[u] @ [W1lo;W1hi] + b1        (K=2048, N=512)
//   Zo[u]   = A2'[u]  @ [W2lo;W2hi]             (K=1024, N=1024), then +b2+res+RMS.
// GEMM1: r5-style 3-deep-A / 2-deep-B (160KB LDS), never-drain counted vmcnt —
//        measured 167us vs paired-K's 185us (per-GEMM A/B across r7/r14).
// GEMM2: r14 paired-K + cache-row substitution (measured ~124us).
// Pipeline: merged cvt+prep launch; GEMM1 tail rows ride in its own grid.

#define EDIM 1024
#define HDIM 512
#define LSEQ 8192
#define BSEQ 8
#define SEQR 8193                 // L+1
#define MTOT (BSEQ * SEQR)        // 65544 extended rows
#define XROWS 66048               // slack rows (zeroed)
#define CVTBLK (XROWS / 4)        // 16512 cvt blocks

using v8s = __attribute__((ext_vector_type(8))) short;
using v4f = __attribute__((ext_vector_type(4))) float;

__device__ __forceinline__ unsigned short f2b(float f) {
  union { float f; unsigned u; } v; v.f = f;
  unsigned r = v.u + 0x7fffu + ((v.u >> 16) & 1u);   // RNE
  return (unsigned short)(r >> 16);
}
__device__ __forceinline__ float b2f(unsigned short h) {
  union { unsigned u; float f; } v; v.u = ((unsigned)h) << 16; return v.f;
}
__device__ __forceinline__ void gl_lds16(const void* g, void* l) {
  __builtin_amdgcn_global_load_lds((const __attribute__((address_space(1))) void*)g,
                                   (__attribute__((address_space(3))) void*)l, 16, 0, 0);
}

// -------- merged cvt + prep: blocks [0,CVTBLK) cvt Xbf; [CVTBLK,+512) weight
// transpose-cat; last block gathers c2b. One launch, prep hides under cvt BW. --------
__device__ __forceinline__ void trns64(const float* __restrict__ src, int src_ld, int src_c0,
                                       unsigned short* __restrict__ dst, int dst_ld, int dst_k0,
                                       int n0, int k0, float (*t)[65], int tx, int ty) {
#pragma unroll
  for (int yy = 0; yy < 64; yy += 4)
    t[yy + ty][tx] = src[(size_t)(k0 + yy + ty) * src_ld + src_c0 + n0 + tx];
  __syncthreads();
#pragma unroll
  for (int yy = 0; yy < 64; yy += 4)
    dst[(size_t)(n0 + yy + ty) * dst_ld + dst_k0 + k0 + tx] = f2b(t[tx][yy + ty]);
}

__global__ __launch_bounds__(256) void cvt_prep(const float* __restrict__ inputs,
                                                const float* __restrict__ lf1,
                                                const float* __restrict__ lf2,
                                                const int* __restrict__ preidx,
                                                const float* __restrict__ W1,
                                                const float* __restrict__ W2,
                                                unsigned short* __restrict__ Xbf,
                                                unsigned short* __restrict__ W1c,
                                                unsigned short* __restrict__ W2c,
                                                unsigned short* __restrict__ c2b) {
  __shared__ float t[64][65];
  const int bk = blockIdx.x;
  const int tid = threadIdx.x;
  if (bk < CVTBLK) {               // ---- cvt: 4 ext rows per block ----
    const int r = bk * 4 + (tid >> 6);
    const int lane = tid & 63;
    unsigned short* dst = Xbf + (size_t)r * EDIM;
    if (r >= MTOT) {
#pragma unroll
      for (int c = lane * 4; c < EDIM; c += 256)
        *(ushort4*)&dst[c] = (ushort4){0, 0, 0, 0};
      return;
    }
    const int b = r / SEQR, rr = r % SEQR;
    const float* src = (rr == 0) ? (lf1 + (size_t)preidx[b] * EDIM)
                                 : (inputs + (size_t)(b * LSEQ + rr - 1) * EDIM);
#pragma unroll
    for (int c = lane * 4; c < EDIM; c += 256) {
      const float4 v = *(const float4*)(src + c);
      *(ushort4*)&dst[c] = (ushort4){f2b(v.x), f2b(v.y), f2b(v.z), f2b(v.w)};
    }
    return;
  }
  if (bk == CVTBLK + 512) {        // ---- c2b gather ----
    for (int c = tid; c < HDIM; c += 256)
#pragma unroll
      for (int b = 0; b < BSEQ; ++b)
        c2b[b * HDIM + c] = f2b(lf2[(size_t)preidx[b] * HDIM + c]);
    return;
  }
  // ---- weight transpose-cat ----
  const int s = bk - CVTBLK;       // 0..511
  const int tx = tid & 63, ty = tid >> 6;
  const int which = s >> 7, ss = s & 127;
  if (which == 0)       trns64(W1, 1024, 0,    W1c, 2048, 0,    (ss & 7) * 64,  (ss >> 3) * 64, t, tx, ty);
  else if (which == 1)  trns64(W1, 1024, 512,  W1c, 2048, 1024, (ss & 7) * 64,  (ss >> 3) * 64, t, tx, ty);
  else if (which == 2)  trns64(W2, 2048, 0,    W2c, 1024, 0,    (ss & 15) * 64, (ss >> 4) * 64, t, tx, ty);
  else                  trns64(W2, 2048, 1024, W2c, 1024, 512,  (ss & 15) * 64, (ss >> 4) * 64, t, tx, ty);
}

// ======= GEMM1: 256x256, BK=64, A 3-deep / B 2-deep (160KB), never-drain ledger =======
// LDS: A bufs @0/@16384/@32768; B bufs @49152/@65536 (elems).
#define PH_A(p, boA_)                                                                  \
  {                                                                                    \
    v8s af[2][2];                                                                      \
    _Pragma("unroll") for (int m2 = 0; m2 < 2; ++m2)                                   \
    _Pragma("unroll") for (int kx = 0; kx < 2; ++kx)                                   \
      af[m2][kx] = *(const v8s*)&lds[(boA_) + ((2 * (p) + m2) * 32 + wm * 16 + lr) * 64 + \
                                     (((kx * 4 + lk) ^ ra7) << 3)];                    \
    __builtin_amdgcn_s_setprio(1);                                                     \
    _Pragma("unroll") for (int m2 = 0; m2 < 2; ++m2)                                   \
    _Pragma("unroll") for (int nc = 0; nc < 4; ++nc)                                   \
    _Pragma("unroll") for (int kx = 0; kx < 2; ++kx)                                   \
      acc[2 * (p) + m2][nc] = __builtin_amdgcn_mfma_f32_16x16x32_bf16(                 \
          af[m2][kx], bf[nc][kx], acc[2 * (p) + m2][nc], 0, 0, 0);                     \
    __builtin_amdgcn_s_setprio(0);                                                     \
  }

#define LB_A(boB_)                                                                     \
  _Pragma("unroll") for (int nc = 0; nc < 4; ++nc)                                     \
  _Pragma("unroll") for (int kx = 0; kx < 2; ++kx)                                     \
    bf[nc][kx] = *(const v8s*)&lds[(boB_) + (nc * 64 + wn * 16 + lr) * 64 +            \
                                   (((kx * 4 + lk) ^ ra7) << 3)];

template <int K, int LDA, int NT, bool SHIFTC, bool TAIL>
__global__ __launch_bounds__(512, 2) void gemm3b(const unsigned short* __restrict__ A,
                                                 const unsigned short* __restrict__ B,
                                                 unsigned short* __restrict__ C,
                                                 const float* __restrict__ bias,
                                                 int q, int r) {
  constexpr int NTILES = K / 64;
  constexpr int N = NT * 256;
  __shared__ __align__(16) unsigned short lds[81920];  // A:3x16384 @0, B:2x16384 @49152

  const int h = blockIdx.x;
  const int mainB = 8 * q + r;

  if constexpr (TAIL) {
    if (h >= mainB) {                  // tail rows 65536..65542 (ext), one col per thread
      const int tid = threadIdx.x;     // 512
      const int rr = 65536 + (h - mainB);
      const unsigned short* a = A + (size_t)rr * LDA;   // 2048 contiguous bf16
      const unsigned short* wrow = B + (size_t)tid * K;
      float s = 0.f;
      for (int k = 0; k < K; k += 8) {
        const v8s av = *(const v8s*)&a[k];
        const v8s wv = *(const v8s*)&wrow[k];
#pragma unroll
        for (int j = 0; j < 8; ++j)
          s += b2f((unsigned short)av[j]) * b2f((unsigned short)wv[j]);
      }
      C[(size_t)(rr + 1) * N + tid] = f2b(s + bias[tid]);
      return;
    }
  }

  const int xcd = h & 7, idx = h >> 3;
  const int tsw = (xcd < r ? xcd * (q + 1) : r * (q + 1) + (xcd - r) * q) + idx;
  const int mt = tsw / NT, nt = tsw % NT;
  const size_t m0 = (size_t)mt * 256, n0 = (size_t)nt * 256;
  const int tid = threadIdx.x;
  const int w = tid >> 6, lane = tid & 63;
  const int wm = w >> 2, wn = w & 3;
  const int lr = lane & 15, lk = lane >> 4;
  const int ra7 = lr & 7;
  const int srow = tid >> 3, slot = tid & 7;
  const int gslot = slot ^ (srow & 7);
  const int dA = srow * 64 + slot * 8;
  const unsigned short* bSrc = B + (size_t)(n0 + srow) * K + gslot * 8;

  auto stageA = [&](int dst, int hh, int tt) {
#pragma unroll
    for (int hf = 0; hf < 2; ++hf) {
      const int u = (int)m0 + hh * 128 + hf * 64 + srow;
      gl_lds16(A + (size_t)u * LDA + tt * 64 + gslot * 8,
               &lds[dst + hh * 8192 + hf * 4096 + dA]);
    }
  };
  auto stageB = [&](int dst, int hh, int tt) {
    const unsigned short* s = bSrc + (size_t)hh * 128 * K + (size_t)tt * 64;
    unsigned short* d = &lds[dst + hh * 8192 + dA];
    gl_lds16(s, d);
    gl_lds16(s + (size_t)64 * K, d + 4096);
  };

  v4f acc[8][4];
#pragma unroll
  for (int i = 0; i < 8; ++i)
#pragma unroll
    for (int j = 0; j < 4; ++j) acc[i][j] = (v4f){0.f, 0.f, 0.f, 0.f};

  // prologue: B(0), A(0), A(1); leave A(1) in flight
  stageB(49152, 0, 0); stageB(49152, 1, 0);
  stageA(0, 0, 0);     stageA(0, 1, 0);
  stageA(16384, 0, 1); stageA(16384, 1, 1);
  asm volatile("s_waitcnt vmcnt(2)" ::: "memory");
  __builtin_amdgcn_s_barrier();

  int boA = 0, soA = 32768;
  int boB = 49152, sB = 65536;
#pragma unroll 1
  for (int t0 = 0; t0 < NTILES - 2; ++t0) {
    v8s bf[4][2];
    stageB(sB, 0, t0 + 1);         // B one tile ahead (L2-resident weights)
    LB_A(boB)
    PH_A(0, boA)
    stageB(sB, 1, t0 + 1);
    PH_A(1, boA)
    stageA(soA, 0, t0 + 2);        // A two tiles ahead (HBM latency cover)
    PH_A(2, boA)
    stageA(soA, 1, t0 + 2);
    PH_A(3, boA)
    // drain B(t0+1) and A(t0+1); leave A(t0+2)'s 4 loads in flight
    asm volatile("s_waitcnt vmcnt(4)" ::: "memory");
    __builtin_amdgcn_s_barrier();
    const int nboA = (boA == 32768) ? 0 : boA + 16384;
    soA = boA; boA = nboA;
    const int tmp = boB; boB = sB; sB = tmp;
  }
  { // tile NTILES-2: stage last B only; full drain at end
    v8s bf[4][2];
    stageB(sB, 0, NTILES - 1);
    LB_A(boB)
    PH_A(0, boA)
    stageB(sB, 1, NTILES - 1);
    PH_A(1, boA)
    PH_A(2, boA)
    PH_A(3, boA)
    asm volatile("s_waitcnt vmcnt(0)" ::: "memory");
    __builtin_amdgcn_s_barrier();
    boA = (boA == 32768) ? 0 : boA + 16384;
    const int tmp = boB; boB = sB; sB = tmp;
  }
  { // tile NTILES-1: everything resident
    v8s bf[4][2];
    LB_A(boB)
    PH_A(0, boA) PH_A(1, boA) PH_A(2, boA) PH_A(3, boA)
  }

#pragma unroll
  for (int mr = 0; mr < 8; ++mr)
#pragma unroll
    for (int nc = 0; nc < 4; ++nc) {
      const size_t col = n0 + nc * 64 + wn * 16 + lr;
      float bv = 0.f;
      if constexpr (SHIFTC) bv = bias[col];
#pragma unroll
      for (int g = 0; g < 4; ++g) {
        const size_t row = m0 + mr * 32 + wm * 16 + lk * 4 + g + (SHIFTC ? 1 : 0);
        C[row * N + col] = f2b(acc[mr][nc][g] + bv);
      }
    }
}

// ======= GEMM2: paired-K 256x256 with cache-row substitution (r14 verbatim) =======
#define PH_P(p, boA_, off_, ra_)                                                       \
  {                                                                                    \
    v8s af[2][2];                                                                      \
    _Pragma("unroll") for (int m2 = 0; m2 < 2; ++m2)                                   \
    _Pragma("unroll") for (int kx = 0; kx < 2; ++kx)                                   \
      af[m2][kx] = *(const v8s*)&lds[(boA_) +                                          \
          ((2 * (p) + m2) * 32 + wm * 16 + lr + (off_)) * 64 +                         \
          (((kx * 4 + lk) ^ (ra_)) << 3)];                                             \
    __builtin_amdgcn_s_setprio(1);                                                     \
    _Pragma("unroll") for (int m2 = 0; m2 < 2; ++m2)                                   \
    _Pragma("unroll") for (int nc = 0; nc < 4; ++nc)                                   \
    _Pragma("unroll") for (int kx = 0; kx < 2; ++kx)                                   \
      acc[2 * (p) + m2][nc] = __builtin_amdgcn_mfma_f32_16x16x32_bf16(                 \
          af[m2][kx], bf[nc][kx], acc[2 * (p) + m2][nc], 0, 0, 0);                     \
    __builtin_amdgcn_s_setprio(0);                                                     \
  }

#define LB_P(boB_)                                                                     \
  _Pragma("unroll") for (int nc = 0; nc < 4; ++nc)                                     \
  _Pragma("unroll") for (int kx = 0; kx < 2; ++kx)                                     \
    bf[nc][kx] = *(const v8s*)&lds[(boB_) + (nc * 64 + wn * 16 + lr) * 64 +            \
                                   (((kx * 4 + lk) ^ ra7a) << 3)];

#define ST_P(boA_, off_, ra_)                                                          \
  PH_P(0, boA_, off_, ra_) PH_P(1, boA_, off_, ra_)                                    \
  PH_P(2, boA_, off_, ra_) PH_P(3, boA_, off_, ra_)

template <int K, int NT>
__global__ __launch_bounds__(512, 2) void gemm_pair(const unsigned short* __restrict__ A,
                                                    const unsigned short* __restrict__ B,
                                                    unsigned short* __restrict__ C,
                                                    const unsigned short* __restrict__ c2b,
                                                    int q, int r) {
  constexpr int NH = K / 128;          // pairs
  constexpr int LDA = K / 2;           // underlying row stride
  constexpr int N = NT * 256;
  constexpr int A0 = 0, A1 = 16512, B_A = 33024, B_B = 49408;   // elem offsets
  __shared__ __align__(16) unsigned short lds[65792];           // 131584 B

  const int h = blockIdx.x;
  const int xcd = h & 7, idx = h >> 3;
  const int tsw = (xcd < r ? xcd * (q + 1) : r * (q + 1) + (xcd - r) * q) + idx;
  const int mt = tsw / NT, nt = tsw % NT;
  const size_t m0 = (size_t)mt * 256, n0 = (size_t)nt * 256;
  const int tid = threadIdx.x;
  const int w = tid >> 6, lane = tid & 63;
  const int wm = w >> 2, wn = w & 3;
  const int lr = lane & 15, lk = lane >> 4;
  const int ra7a = lr & 7, ra7b = (lr + 1) & 7;
  const int srow = tid >> 3, slot = tid & 7;
  const int gslot = slot ^ (srow & 7);
  const int dAB = srow * 64 + slot * 8;
  const int aBase = (int)m0 + ((int)m0 >> 13);

  // A source for underlying ext row `row`, pair i, 16B-slot `sl` (cache-row substitute)
  auto aSrc = [&](int row, int i, int sl) -> const unsigned short* {
    if ((row >> 13) == (row & 8191))                      // row == b*8193 (b<8)
      return c2b + (size_t)(row >> 13) * HDIM + i * 64 + sl * 8;
    return A + (size_t)row * LDA + i * 64 + sl * 8;
  };
  auto stageApair = [&](int dstE, int i) {
#pragma unroll
    for (int j = 0; j < 4; ++j) {
      const int rr = j * 64 + (tid >> 3);
      gl_lds16(aSrc(aBase + rr, i, (tid & 7) ^ (rr & 7)),
               &lds[dstE + rr * 64 + (tid & 7) * 8]);
    }
    if (tid < 8)
      gl_lds16(aSrc(aBase + 256, i, tid),
               &lds[dstE + 256 * 64 + tid * 8]);
  };
  auto stageB = [&](int dstE, int hh, int t) {
    const unsigned short* s = B + (size_t)(n0 + hh * 128 + srow) * K + t * 64 + gslot * 8;
    unsigned short* d = &lds[dstE + hh * 8192 + dAB];
    gl_lds16(s, d);
    gl_lds16(s + (size_t)64 * K, d + 4096);
  };

  v4f acc[8][4];
#pragma unroll
  for (int i = 0; i < 8; ++i)
#pragma unroll
    for (int j = 0; j < 4; ++j) acc[i][j] = (v4f){0.f, 0.f, 0.f, 0.f};

  stageApair(A0, 0);
  stageB(B_A, 0, 0); stageB(B_A, 1, 0);
  asm volatile("s_waitcnt vmcnt(0)" ::: "memory");
  __builtin_amdgcn_s_barrier();

#pragma unroll 1
  for (int i = 0; i < NH - 1; ++i) {
    const int boA = (i & 1) ? A1 : A0;
    const int soA = (i & 1) ? A0 : A1;
    v8s bf[4][2];
    stageB(B_B, 0, i + NH); stageB(B_B, 1, i + NH);
    stageApair(soA, i + 1);
    LB_P(B_A)
    ST_P(boA, 0, ra7a)
    asm volatile("s_waitcnt vmcnt(4)" ::: "memory");
    __builtin_amdgcn_s_barrier();
    stageB(B_A, 0, i + 1); stageB(B_A, 1, i + 1);
    LB_P(B_B)
    ST_P(boA, 1, ra7b)
    asm volatile("s_waitcnt vmcnt(0)" ::: "memory");
    __builtin_amdgcn_s_barrier();
  }
  {
    const int boA = ((NH - 1) & 1) ? A1 : A0;
    v8s bf[4][2];
    stageB(B_B, 0, 2 * NH - 1); stageB(B_B, 1, 2 * NH - 1);
    LB_P(B_A)
    ST_P(boA, 0, ra7a)
    asm volatile("s_waitcnt vmcnt(0)" ::: "memory");
    __builtin_amdgcn_s_barrier();
    LB_P(B_B)
    ST_P(boA, 1, ra7b)
  }

#pragma unroll
  for (int mr = 0; mr < 8; ++mr)
#pragma unroll
    for (int nc = 0; nc < 4; ++nc) {
      const size_t col = n0 + nc * 64 + wn * 16 + lr;
#pragma unroll
      for (int g = 0; g < 4; ++g) {
        const size_t row = m0 + mr * 32 + wm * 16 + lk * 4 + g;
        C[row * N + col] = f2b(acc[mr][nc][g]);
      }
    }
}

// ---------- epilogue: + b2 + residual(bf16 Xbf) + RMSNorm, one block per token ----------
__global__ __launch_bounds__(256) void epilogue_full(
    const unsigned short* __restrict__ Zo, const unsigned short* __restrict__ Xbf,
    const float* __restrict__ b2, const float* __restrict__ lnw,
    float* __restrict__ out) {
  const int u = blockIdx.x;                       // token id 0..65535
  const size_t rx = (size_t)u + (u >> 13) + 1;    // token's ext row in Xbf
  const int tid = threadIdx.x;
  const int j0 = tid * 4;

  const ushort4 z = *(const ushort4*)&Zo[(size_t)u * EDIM + j0];
  const ushort4 xb = *(const ushort4*)&Xbf[rx * EDIM + j0];   // = bf16(inputs[token])
  const float4 bb = *(const float4*)&b2[j0];
  const float4 lw = *(const float4*)&lnw[j0];

  const float x0 = b2f(z.x) + bb.x + b2f(xb.x);
  const float x1 = b2f(z.y) + bb.y + b2f(xb.y);
  const float x2 = b2f(z.z) + bb.z + b2f(xb.z);
  const float x3 = b2f(z.w) + bb.w + b2f(xb.w);

  float ss = x0 * x0 + x1 * x1 + x2 * x2 + x3 * x3;
#pragma unroll
  for (int o = 32; o > 0; o >>= 1) ss += __shfl_xor(ss, o, 64);
  __shared__ float sp[4];
  if ((tid & 63) == 0) sp[tid >> 6] = ss;
  __syncthreads();
  const float tot = sp[0] + sp[1] + sp[2] + sp[3];
  const float scale = rsqrtf(tot * (1.0f / EDIM) + 1e-6f);

  float4 o4;
  o4.x = x0 * scale * lw.x; o4.y = x1 * scale * lw.y;
  o4.z = x2 * scale * lw.z; o4.w = x3 * scale * lw.w;
  *(float4*)&out[(size_t)u * EDIM + j0] = o4;
}

// -------------------------------- launch --------------------------------
extern "C" void kernel_launch(void* const* d_in, const int* in_sizes, int n_in,
                              void* d_out, int out_size, void* d_ws, size_t ws_size,
                              hipStream_t stream) {
  const float* inputs = (const float*)d_in[0];
  const float* W1 = (const float*)d_in[1];
  const float* W2 = (const float*)d_in[2];
  const float* b1 = (const float*)d_in[3];
  const float* b2 = (const float*)d_in[4];
  const float* lnw = (const float*)d_in[5];
  const float* lf1 = (const float*)d_in[6];
  const float* lf2 = (const float*)d_in[7];
  const int* preidx = (const int*)d_in[8];
  float* out = (float*)d_out;

  char* ws = (char*)d_ws;
  unsigned short* Xbf = (unsigned short*)(ws);                 // XROWS x 1024 = 135,266,304 B
  unsigned short* A2  = (unsigned short*)(ws + 135266304ULL);  // XROWS x  512 =  67,633,152 B
  unsigned short* Zo  = (unsigned short*)(ws + 202899456ULL);  // 65536 x 1024 = 134,217,728 B
  unsigned short* W1c = (unsigned short*)(ws + 337117184ULL);  //  512 x 2048 bf16
  unsigned short* W2c = (unsigned short*)(ws + 339214336ULL);  // 1024 x 1024 bf16
  unsigned short* c2b = (unsigned short*)(ws + 341311488ULL);  // 8 x 512
  // total ws use: ~341 MB

  // merged cvt + weight prep + c2b (one launch; prep hides under BW-bound cvt)
  cvt_prep<<<CVTBLK + 513, 256, 0, stream>>>(inputs, lf1, lf2, preidx, W1, W2,
                                             Xbf, W1c, W2c, c2b);
  // GEMM1: M=65536 x N=512, K=2048 -> 512 main blocks + 7 tail blocks; 3A/2B schedule
  gemm3b<2048, 1024, 2, true, true>
      <<<519, 512, 0, stream>>>(Xbf, W1c, A2, b1, 64, 0);
  // GEMM2: M=65536 x N=1024, K=1024 (NH=8 pairs) -> 1024 blocks; cache rows from c2b
  gemm_pair<1024, 4>
      <<<1024, 512, 0, stream>>>(A2, W2c, Zo, c2b, 128, 0);
  epilogue_full<<<BSEQ * LSEQ, 256, 0, stream>>>(Zo, Xbf, b2, lnw, out);
}

// Round 16
// 445.021 us; speedup vs baseline: 1.0458x; 1.0458x over previous
//
#include <hip/hip_runtime.h>
#include <hip/hip_bf16.h>

// LocalizedFiltering: two shifted 2-tap causal convs + residual + RMSNorm.
// Fused-K form: A'[u] = U[u] ‖ U[u+1] (U = Xbf for GEMM1, A2 for GEMM2):
//   A2[u+1] = Xbf'[u] @ [W1lo;W1hi] + b1        (K=2048, N=512)
//   Zo[u]   = A2'[u]  @ [W2lo;W2hi]             (K=1024, N=1024), then +b2+res+RMS.
// GEMM1: r5 gemm3b verbatim — 3-deep-A / 2-deep-B (160KB LDS), never-drain
//        counted vmcnt, M=65792 (257 m-tiles, grid 514) so tail rows are
//        covered by the main GEMM (no tail blocks: r15 showed a 7-block third
//        wave costs ~20us). Measured 165us in r5.
// GEMM2: r14 paired-K + cache-row substitution verbatim (measured ~124us).
// No fixup kernel at all. Merged cvt+prep launch.

#define EDIM 1024
#define HDIM 512
#define LSEQ 8192
#define BSEQ 8
#define SEQR 8193                 // L+1
#define MTOT (BSEQ * SEQR)        // 65544 extended rows
#define XROWS 66048               // slack rows (zeroed)
#define CVTBLK (XROWS / 4)        // 16512 cvt blocks

using v8s = __attribute__((ext_vector_type(8))) short;
using v4f = __attribute__((ext_vector_type(4))) float;

__device__ __forceinline__ unsigned short f2b(float f) {
  union { float f; unsigned u; } v; v.f = f;
  unsigned r = v.u + 0x7fffu + ((v.u >> 16) & 1u);   // RNE
  return (unsigned short)(r >> 16);
}
__device__ __forceinline__ float b2f(unsigned short h) {
  union { unsigned u; float f; } v; v.u = ((unsigned)h) << 16; return v.f;
}
__device__ __forceinline__ void gl_lds16(const void* g, void* l) {
  __builtin_amdgcn_global_load_lds((const __attribute__((address_space(1))) void*)g,
                                   (__attribute__((address_space(3))) void*)l, 16, 0, 0);
}

// -------- merged cvt + prep: blocks [0,CVTBLK) cvt Xbf; [CVTBLK,+512) weight
// transpose-cat; last block gathers c2b. One launch, prep hides under cvt BW. --------
__device__ __forceinline__ void trns64(const float* __restrict__ src, int src_ld, int src_c0,
                                       unsigned short* __restrict__ dst, int dst_ld, int dst_k0,
                                       int n0, int k0, float (*t)[65], int tx, int ty) {
#pragma unroll
  for (int yy = 0; yy < 64; yy += 4)
    t[yy + ty][tx] = src[(size_t)(k0 + yy + ty) * src_ld + src_c0 + n0 + tx];
  __syncthreads();
#pragma unroll
  for (int yy = 0; yy < 64; yy += 4)
    dst[(size_t)(n0 + yy + ty) * dst_ld + dst_k0 + k0 + tx] = f2b(t[tx][yy + ty]);
}

__global__ __launch_bounds__(256) void cvt_prep(const float* __restrict__ inputs,
                                                const float* __restrict__ lf1,
                                                const float* __restrict__ lf2,
                                                const int* __restrict__ preidx,
                                                const float* __restrict__ W1,
                                                const float* __restrict__ W2,
                                                unsigned short* __restrict__ Xbf,
                                                unsigned short* __restrict__ W1c,
                                                unsigned short* __restrict__ W2c,
                                                unsigned short* __restrict__ c2b) {
  __shared__ float t[64][65];
  const int bk = blockIdx.x;
  const int tid = threadIdx.x;
  if (bk < CVTBLK) {               // ---- cvt: 4 ext rows per block ----
    const int r = bk * 4 + (tid >> 6);
    const int lane = tid & 63;
    unsigned short* dst = Xbf + (size_t)r * EDIM;
    if (r >= MTOT) {
#pragma unroll
      for (int c = lane * 4; c < EDIM; c += 256)
        *(ushort4*)&dst[c] = (ushort4){0, 0, 0, 0};
      return;
    }
    const int b = r / SEQR, rr = r % SEQR;
    const float* src = (rr == 0) ? (lf1 + (size_t)preidx[b] * EDIM)
                                 : (inputs + (size_t)(b * LSEQ + rr - 1) * EDIM);
#pragma unroll
    for (int c = lane * 4; c < EDIM; c += 256) {
      const float4 v = *(const float4*)(src + c);
      *(ushort4*)&dst[c] = (ushort4){f2b(v.x), f2b(v.y), f2b(v.z), f2b(v.w)};
    }
    return;
  }
  if (bk == CVTBLK + 512) {        // ---- c2b gather ----
    for (int c = tid; c < HDIM; c += 256)
#pragma unroll
      for (int b = 0; b < BSEQ; ++b)
        c2b[b * HDIM + c] = f2b(lf2[(size_t)preidx[b] * HDIM + c]);
    return;
  }
  // ---- weight transpose-cat ----
  const int s = bk - CVTBLK;       // 0..511
  const int tx = tid & 63, ty = tid >> 6;
  const int which = s >> 7, ss = s & 127;
  if (which == 0)       trns64(W1, 1024, 0,    W1c, 2048, 0,    (ss & 7) * 64,  (ss >> 3) * 64, t, tx, ty);
  else if (which == 1)  trns64(W1, 1024, 512,  W1c, 2048, 1024, (ss & 7) * 64,  (ss >> 3) * 64, t, tx, ty);
  else if (which == 2)  trns64(W2, 2048, 0,    W2c, 1024, 0,    (ss & 15) * 64, (ss >> 4) * 64, t, tx, ty);
  else                  trns64(W2, 2048, 1024, W2c, 1024, 512,  (ss & 15) * 64, (ss >> 4) * 64, t, tx, ty);
}

// ======= GEMM1: 256x256, BK=64, A 3-deep / B 2-deep (160KB), never-drain ledger =======
// LDS: A bufs @0/@16384/@32768; B bufs @49152/@65536 (elems). M=65792 (grid 514).
#define PH_A(p, boA_)                                                                  \
  {                                                                                    \
    v8s af[2][2];                                                                      \
    _Pragma("unroll") for (int m2 = 0; m2 < 2; ++m2)                                   \
    _Pragma("unroll") for (int kx = 0; kx < 2; ++kx)                                   \
      af[m2][kx] = *(const v8s*)&lds[(boA_) + ((2 * (p) + m2) * 32 + wm * 16 + lr) * 64 + \
                                     (((kx * 4 + lk) ^ ra7) << 3)];                    \
    __builtin_amdgcn_s_setprio(1);                                                     \
    _Pragma("unroll") for (int m2 = 0; m2 < 2; ++m2)                                   \
    _Pragma("unroll") for (int nc = 0; nc < 4; ++nc)                                   \
    _Pragma("unroll") for (int kx = 0; kx < 2; ++kx)                                   \
      acc[2 * (p) + m2][nc] = __builtin_amdgcn_mfma_f32_16x16x32_bf16(                 \
          af[m2][kx], bf[nc][kx], acc[2 * (p) + m2][nc], 0, 0, 0);                     \
    __builtin_amdgcn_s_setprio(0);                                                     \
  }

#define LB_A(boB_)                                                                     \
  _Pragma("unroll") for (int nc = 0; nc < 4; ++nc)                                     \
  _Pragma("unroll") for (int kx = 0; kx < 2; ++kx)                                     \
    bf[nc][kx] = *(const v8s*)&lds[(boB_) + (nc * 64 + wn * 16 + lr) * 64 +            \
                                   (((kx * 4 + lk) ^ ra7) << 3)];

template <int K, int LDA, int NT, bool SHIFTC>
__global__ __launch_bounds__(512, 2) void gemm3b(const unsigned short* __restrict__ A,
                                                 const unsigned short* __restrict__ B,
                                                 unsigned short* __restrict__ C,
                                                 const float* __restrict__ bias,
                                                 int q, int r) {
  constexpr int NTILES = K / 64;
  constexpr int N = NT * 256;
  __shared__ __align__(16) unsigned short lds[81920];  // A:3x16384 @0, B:2x16384 @49152

  const int h = blockIdx.x;
  const int xcd = h & 7, idx = h >> 3;
  const int tsw = (xcd < r ? xcd * (q + 1) : r * (q + 1) + (xcd - r) * q) + idx;
  const int mt = tsw / NT, nt = tsw % NT;
  const size_t m0 = (size_t)mt * 256, n0 = (size_t)nt * 256;
  const int tid = threadIdx.x;
  const int w = tid >> 6, lane = tid & 63;
  const int wm = w >> 2, wn = w & 3;
  const int lr = lane & 15, lk = lane >> 4;
  const int ra7 = lr & 7;
  const int srow = tid >> 3, slot = tid & 7;
  const int gslot = slot ^ (srow & 7);
  const int dA = srow * 64 + slot * 8;
  const unsigned short* bSrc = B + (size_t)(n0 + srow) * K + gslot * 8;

  auto stageA = [&](int dst, int hh, int tt) {
#pragma unroll
    for (int hf = 0; hf < 2; ++hf) {
      const int u = (int)m0 + hh * 128 + hf * 64 + srow;
      gl_lds16(A + (size_t)u * LDA + tt * 64 + gslot * 8,
               &lds[dst + hh * 8192 + hf * 4096 + dA]);
    }
  };
  auto stageB = [&](int dst, int hh, int tt) {
    const unsigned short* s = bSrc + (size_t)hh * 128 * K + (size_t)tt * 64;
    unsigned short* d = &lds[dst + hh * 8192 + dA];
    gl_lds16(s, d);
    gl_lds16(s + (size_t)64 * K, d + 4096);
  };

  v4f acc[8][4];
#pragma unroll
  for (int i = 0; i < 8; ++i)
#pragma unroll
    for (int j = 0; j < 4; ++j) acc[i][j] = (v4f){0.f, 0.f, 0.f, 0.f};

  // prologue: B(0), A(0), A(1); leave A(1) in flight
  stageB(49152, 0, 0); stageB(49152, 1, 0);
  stageA(0, 0, 0);     stageA(0, 1, 0);
  stageA(16384, 0, 1); stageA(16384, 1, 1);
  asm volatile("s_waitcnt vmcnt(2)" ::: "memory");
  __builtin_amdgcn_s_barrier();

  int boA = 0, soA = 32768;
  int boB = 49152, sB = 65536;
#pragma unroll 1
  for (int t0 = 0; t0 < NTILES - 2; ++t0) {
    v8s bf[4][2];
    stageB(sB, 0, t0 + 1);         // B one tile ahead (L2-resident weights)
    LB_A(boB)
    PH_A(0, boA)
    stageB(sB, 1, t0 + 1);
    PH_A(1, boA)
    stageA(soA, 0, t0 + 2);        // A two tiles ahead (HBM latency cover)
    PH_A(2, boA)
    stageA(soA, 1, t0 + 2);
    PH_A(3, boA)
    // drain B(t0+1) and A(t0+1); leave A(t0+2)'s 4 loads in flight
    asm volatile("s_waitcnt vmcnt(4)" ::: "memory");
    __builtin_amdgcn_s_barrier();
    const int nboA = (boA == 32768) ? 0 : boA + 16384;
    soA = boA; boA = nboA;
    const int tmp = boB; boB = sB; sB = tmp;
  }
  { // tile NTILES-2: stage last B only; full drain at end
    v8s bf[4][2];
    stageB(sB, 0, NTILES - 1);
    LB_A(boB)
    PH_A(0, boA)
    stageB(sB, 1, NTILES - 1);
    PH_A(1, boA)
    PH_A(2, boA)
    PH_A(3, boA)
    asm volatile("s_waitcnt vmcnt(0)" ::: "memory");
    __builtin_amdgcn_s_barrier();
    boA = (boA == 32768) ? 0 : boA + 16384;
    const int tmp = boB; boB = sB; sB = tmp;
  }
  { // tile NTILES-1: everything resident
    v8s bf[4][2];
    LB_A(boB)
    PH_A(0, boA) PH_A(1, boA) PH_A(2, boA) PH_A(3, boA)
  }

#pragma unroll
  for (int mr = 0; mr < 8; ++mr)
#pragma unroll
    for (int nc = 0; nc < 4; ++nc) {
      const size_t col = n0 + nc * 64 + wn * 16 + lr;
      float bv = 0.f;
      if constexpr (SHIFTC) bv = bias[col];
#pragma unroll
      for (int g = 0; g < 4; ++g) {
        const size_t row = m0 + mr * 32 + wm * 16 + lk * 4 + g + (SHIFTC ? 1 : 0);
        C[row * N + col] = f2b(acc[mr][nc][g] + bv);
      }
    }
}

// ======= GEMM2: paired-K 256x256 with cache-row substitution (r14 verbatim) =======
#define PH_P(p, boA_, off_, ra_)                                                       \
  {                                                                                    \
    v8s af[2][2];                                                                      \
    _Pragma("unroll") for (int m2 = 0; m2 < 2; ++m2)                                   \
    _Pragma("unroll") for (int kx = 0; kx < 2; ++kx)                                   \
      af[m2][kx] = *(const v8s*)&lds[(boA_) +                                          \
          ((2 * (p) + m2) * 32 + wm * 16 + lr + (off_)) * 64 +                         \
          (((kx * 4 + lk) ^ (ra_)) << 3)];                                             \
    __builtin_amdgcn_s_setprio(1);                                                     \
    _Pragma("unroll") for (int m2 = 0; m2 < 2; ++m2)                                   \
    _Pragma("unroll") for (int nc = 0; nc < 4; ++nc)                                   \
    _Pragma("unroll") for (int kx = 0; kx < 2; ++kx)                                   \
      acc[2 * (p) + m2][nc] = __builtin_amdgcn_mfma_f32_16x16x32_bf16(                 \
          af[m2][kx], bf[nc][kx], acc[2 * (p) + m2][nc], 0, 0, 0);                     \
    __builtin_amdgcn_s_setprio(0);                                                     \
  }

#define LB_P(boB_)                                                                     \
  _Pragma("unroll") for (int nc = 0; nc < 4; ++nc)                                     \
  _Pragma("unroll") for (int kx = 0; kx < 2; ++kx)                                     \
    bf[nc][kx] = *(const v8s*)&lds[(boB_) + (nc * 64 + wn * 16 + lr) * 64 +            \
                                   (((kx * 4 + lk) ^ ra7a) << 3)];

#define ST_P(boA_, off_, ra_)                                                          \
  PH_P(0, boA_, off_, ra_) PH_P(1, boA_, off_, ra_)                                    \
  PH_P(2, boA_, off_, ra_) PH_P(3, boA_, off_, ra_)

template <int K, int NT>
__global__ __launch_bounds__(512, 2) void gemm_pair(const unsigned short* __restrict__ A,
                                                    const unsigned short* __restrict__ B,
                                                    unsigned short* __restrict__ C,
                                                    const unsigned short* __restrict__ c2b,
                                                    int q, int r) {
  constexpr int NH = K / 128;          // pairs
  constexpr int LDA = K / 2;           // underlying row stride
  constexpr int N = NT * 256;
  constexpr int A0 = 0, A1 = 16512, B_A = 33024, B_B = 49408;   // elem offsets
  __shared__ __align__(16) unsigned short lds[65792];           // 131584 B

  const int h = blockIdx.x;
  const int xcd = h & 7, idx = h >> 3;
  const int tsw = (xcd < r ? xcd * (q + 1) : r * (q + 1) + (xcd - r) * q) + idx;
  const int mt = tsw / NT, nt = tsw % NT;
  const size_t m0 = (size_t)mt * 256, n0 = (size_t)nt * 256;
  const int tid = threadIdx.x;
  const int w = tid >> 6, lane = tid & 63;
  const int wm = w >> 2, wn = w & 3;
  const int lr = lane & 15, lk = lane >> 4;
  const int ra7a = lr & 7, ra7b = (lr + 1) & 7;
  const int srow = tid >> 3, slot = tid & 7;
  const int gslot = slot ^ (srow & 7);
  const int dAB = srow * 64 + slot * 8;
  const int aBase = (int)m0 + ((int)m0 >> 13);

  // A source for underlying ext row `row`, pair i, 16B-slot `sl` (cache-row substitute)
  auto aSrc = [&](int row, int i, int sl) -> const unsigned short* {
    if ((row >> 13) == (row & 8191))                      // row == b*8193 (b<8)
      return c2b + (size_t)(row >> 13) * HDIM + i * 64 + sl * 8;
    return A + (size_t)row * LDA + i * 64 + sl * 8;
  };
  auto stageApair = [&](int dstE, int i) {
#pragma unroll
    for (int j = 0; j < 4; ++j) {
      const int rr = j * 64 + (tid >> 3);
      gl_lds16(aSrc(aBase + rr, i, (tid & 7) ^ (rr & 7)),
               &lds[dstE + rr * 64 + (tid & 7) * 8]);
    }
    if (tid < 8)
      gl_lds16(aSrc(aBase + 256, i, tid),
               &lds[dstE + 256 * 64 + tid * 8]);
  };
  auto stageB = [&](int dstE, int hh, int t) {
    const unsigned short* s = B + (size_t)(n0 + hh * 128 + srow) * K + t * 64 + gslot * 8;
    unsigned short* d = &lds[dstE + hh * 8192 + dAB];
    gl_lds16(s, d);
    gl_lds16(s + (size_t)64 * K, d + 4096);
  };

  v4f acc[8][4];
#pragma unroll
  for (int i = 0; i < 8; ++i)
#pragma unroll
    for (int j = 0; j < 4; ++j) acc[i][j] = (v4f){0.f, 0.f, 0.f, 0.f};

  stageApair(A0, 0);
  stageB(B_A, 0, 0); stageB(B_A, 1, 0);
  asm volatile("s_waitcnt vmcnt(0)" ::: "memory");
  __builtin_amdgcn_s_barrier();

#pragma unroll 1
  for (int i = 0; i < NH - 1; ++i) {
    const int boA = (i & 1) ? A1 : A0;
    const int soA = (i & 1) ? A0 : A1;
    v8s bf[4][2];
    stageB(B_B, 0, i + NH); stageB(B_B, 1, i + NH);
    stageApair(soA, i + 1);
    LB_P(B_A)
    ST_P(boA, 0, ra7a)
    asm volatile("s_waitcnt vmcnt(4)" ::: "memory");
    __builtin_amdgcn_s_barrier();
    stageB(B_A, 0, i + 1); stageB(B_A, 1, i + 1);
    LB_P(B_B)
    ST_P(boA, 1, ra7b)
    asm volatile("s_waitcnt vmcnt(0)" ::: "memory");
    __builtin_amdgcn_s_barrier();
  }
  {
    const int boA = ((NH - 1) & 1) ? A1 : A0;
    v8s bf[4][2];
    stageB(B_B, 0, 2 * NH - 1); stageB(B_B, 1, 2 * NH - 1);
    LB_P(B_A)
    ST_P(boA, 0, ra7a)
    asm volatile("s_waitcnt vmcnt(0)" ::: "memory");
    __builtin_amdgcn_s_barrier();
    LB_P(B_B)
    ST_P(boA, 1, ra7b)
  }

#pragma unroll
  for (int mr = 0; mr < 8; ++mr)
#pragma unroll
    for (int nc = 0; nc < 4; ++nc) {
      const size_t col = n0 + nc * 64 + wn * 16 + lr;
#pragma unroll
      for (int g = 0; g < 4; ++g) {
        const size_t row = m0 + mr * 32 + wm * 16 + lk * 4 + g;
        C[row * N + col] = f2b(acc[mr][nc][g]);
      }
    }
}

// ---------- epilogue: + b2 + residual(bf16 Xbf) + RMSNorm, one block per token ----------
__global__ __launch_bounds__(256) void epilogue_full(
    const unsigned short* __restrict__ Zo, const unsigned short* __restrict__ Xbf,
    const float* __restrict__ b2, const float* __restrict__ lnw,
    float* __restrict__ out) {
  const int u = blockIdx.x;                       // token id 0..65535
  const size_t rx = (size_t)u + (u >> 13) + 1;    // token's ext row in Xbf
  const int tid = threadIdx.x;
  const int j0 = tid * 4;

  const ushort4 z = *(const ushort4*)&Zo[(size_t)u * EDIM + j0];
  const ushort4 xb = *(const ushort4*)&Xbf[rx * EDIM + j0];   // = bf16(inputs[token])
  const float4 bb = *(const float4*)&b2[j0];
  const float4 lw = *(const float4*)&lnw[j0];

  const float x0 = b2f(z.x) + bb.x + b2f(xb.x);
  const float x1 = b2f(z.y) + bb.y + b2f(xb.y);
  const float x2 = b2f(z.z) + bb.z + b2f(xb.z);
  const float x3 = b2f(z.w) + bb.w + b2f(xb.w);

  float ss = x0 * x0 + x1 * x1 + x2 * x2 + x3 * x3;
#pragma unroll
  for (int o = 32; o > 0; o >>= 1) ss += __shfl_xor(ss, o, 64);
  __shared__ float sp[4];
  if ((tid & 63) == 0) sp[tid >> 6] = ss;
  __syncthreads();
  const float tot = sp[0] + sp[1] + sp[2] + sp[3];
  const float scale = rsqrtf(tot * (1.0f / EDIM) + 1e-6f);

  float4 o4;
  o4.x = x0 * scale * lw.x; o4.y = x1 * scale * lw.y;
  o4.z = x2 * scale * lw.z; o4.w = x3 * scale * lw.w;
  *(float4*)&out[(size_t)u * EDIM + j0] = o4;
}

// -------------------------------- launch --------------------------------
extern "C" void kernel_launch(void* const* d_in, const int* in_sizes, int n_in,
                              void* d_out, int out_size, void* d_ws, size_t ws_size,
                              hipStream_t stream) {
  const float* inputs = (const float*)d_in[0];
  const float* W1 = (const float*)d_in[1];
  const float* W2 = (const float*)d_in[2];
  const float* b1 = (const float*)d_in[3];
  const float* b2 = (const float*)d_in[4];
  const float* lnw = (const float*)d_in[5];
  const float* lf1 = (const float*)d_in[6];
  const float* lf2 = (const float*)d_in[7];
  const int* preidx = (const int*)d_in[8];
  float* out = (float*)d_out;

  char* ws = (char*)d_ws;
  unsigned short* Xbf = (unsigned short*)(ws);                 // XROWS x 1024 = 135,266,304 B
  unsigned short* A2  = (unsigned short*)(ws + 135266304ULL);  // XROWS x  512 =  67,633,152 B
  unsigned short* Zo  = (unsigned short*)(ws + 202899456ULL);  // 65536 x 1024 = 134,217,728 B
  unsigned short* W1c = (unsigned short*)(ws + 337117184ULL);  //  512 x 2048 bf16
  unsigned short* W2c = (unsigned short*)(ws + 339214336ULL);  // 1024 x 1024 bf16
  unsigned short* c2b = (unsigned short*)(ws + 341311488ULL);  // 8 x 512
  // total ws use: ~341 MB

  // merged cvt + weight prep + c2b (one launch; prep hides under BW-bound cvt)
  cvt_prep<<<CVTBLK + 513, 256, 0, stream>>>(inputs, lf1, lf2, preidx, W1, W2,
                                             Xbf, W1c, W2c, c2b);
  // GEMM1: M=65792 (257 m-tiles) x N=512 (2 n-tiles) -> 514 blocks; q=64, r=2
  // (covers tail rows in the main GEMM; cache rows of A2 handled by GEMM2's CSUB)
  gemm3b<2048, 1024, 2, true>
      <<<514, 512, 0, stream>>>(Xbf, W1c, A2, b1, 64, 2);
  // GEMM2: M=65536 x N=1024, K=1024 (NH=8 pairs) -> 1024 blocks; cache rows from c2b
  gemm_pair<1024, 4>
      <<<1024, 512, 0, stream>>>(A2, W2c, Zo, c2b, 128, 0);
  epilogue_full<<<BSEQ * LSEQ, 256, 0, stream>>>(Zo, Xbf, b2, lnw, out);
}